// Round 1
// baseline (280.879 us; speedup 1.0000x reference)
//
#include <hip/hip_runtime.h>

#define HW 16384        // 128*128
#define W_IMG 128
#define BM_TOT 5        // B*M = 1*5
#define SCALE 0.35355339059327373f  // 1/sqrt(8)

// ---------------------------------------------------------------------------
// Kernel 1: 1x1 conv (3->64) + LayerNorm + QKV projection.
// One wave per pixel, lane = channel e.
// Outputs: feat (BM,HW,64), qmid (HW,64) [center frame only], kbuf/vbuf (BM,HW,64)
// ---------------------------------------------------------------------------
__global__ __launch_bounds__(256) void k_qkv(
    const float* __restrict__ x, const float* __restrict__ w_high,
    const float* __restrict__ b_high, const float* __restrict__ gamma,
    const float* __restrict__ beta, const float* __restrict__ w_qkv,
    float* __restrict__ feat, float* __restrict__ qmid,
    float* __restrict__ kbuf, float* __restrict__ vbuf)
{
    // w_qkv transposed into LDS: wq[e*193 + j] = w_qkv[j*64 + e]
    // stride 193 (193%32==1) -> conflict-free transpose-write AND compute-read.
    __shared__ float wq[64 * 193];
    const int tid = threadIdx.x;
    for (int idx = tid; idx < 192 * 64; idx += 256) {
        int j = idx >> 6, e = idx & 63;
        wq[e * 193 + j] = w_qkv[idx];
    }
    __syncthreads();

    const int lane = tid & 63, wave = tid >> 6;
    const float wh0 = w_high[lane * 3 + 0];
    const float wh1 = w_high[lane * 3 + 1];
    const float wh2 = w_high[lane * 3 + 2];
    const float bh = b_high[lane], g = gamma[lane], bb = beta[lane];

    const int step = gridDim.x * 4;
    for (int pix = blockIdx.x * 4 + wave; pix < BM_TOT * HW; pix += step) {
        const int bm = pix >> 14;
        const int p = pix & (HW - 1);
        const float* xp = x + (size_t)bm * 3 * HW + p;
        const float x0 = xp[0], x1 = xp[HW], x2 = xp[2 * HW];
        float f = fmaf(wh0, x0, fmaf(wh1, x1, fmaf(wh2, x2, bh)));
        feat[(size_t)pix * 64 + lane] = f;

        // LayerNorm over the 64 lanes
        float s = f, s2 = f * f;
        #pragma unroll
        for (int o = 32; o; o >>= 1) { s += __shfl_xor(s, o); s2 += __shfl_xor(s2, o); }
        const float mu = s * 0.015625f;
        const float var = s2 * 0.015625f - mu * mu;
        const float xs = (f - mu) * rsqrtf(var + 1e-6f) * g + bb;

        // qkv: lane computes output channels {lane, lane+64, lane+128}
        float aq = 0.f, ak = 0.f, av = 0.f;
        #pragma unroll
        for (int e = 0; e < 64; ++e) {
            const float xe = __shfl(xs, e);          // unrolled -> v_readlane
            const float* row = wq + e * 193;
            aq = fmaf(xe, row[lane], aq);
            ak = fmaf(xe, row[64 + lane], ak);
            av = fmaf(xe, row[128 + lane], av);
        }
        if (bm == 2) qmid[(size_t)p * 64 + lane] = aq;  // B=1, center frame M//2=2
        kbuf[(size_t)pix * 64 + lane] = ak;
        vbuf[(size_t)pix * 64 + lane] = av;
    }
}

// ---------------------------------------------------------------------------
// Kernel 2: windowed attention + out-proj + residual + RGB, fully fused.
// One block per window (bm, wi, wj); 512 threads; thread = (head, qpos).
// K/V staged in LDS in two 72-key chunks (static LDS 36864 B).
// ---------------------------------------------------------------------------
__global__ __launch_bounds__(512) void k_attn(
    const float* __restrict__ qmid, const float* __restrict__ kbuf,
    const float* __restrict__ vbuf, const float* __restrict__ pos_q,
    const float* __restrict__ pos_k, const float* __restrict__ w_out,
    const float* __restrict__ w_rgb, const float* __restrict__ b_rgb,
    const float* __restrict__ feat, float* __restrict__ outp)
{
    __shared__ float lds[72 * 64 * 2];      // 36864 B
    float* Kt = lds;                        // [72*64] chunk of K (+pos_k)
    float* Vt = lds + 72 * 64;              // [72*64]
    float* outt = lds;                      // reuse: [64*65] attn out (padded)
    float* wot  = lds + 64 * 65;            // reuse: [64*64] w_out transposed

    const int tid = threadIdx.x;
    const int blk = blockIdx.x;
    const int bm = blk >> 8;                // window order: bm, wi, wj
    const int widx = blk & 255;
    const int wi = widx >> 4, wj = widx & 15;

    const int head = tid >> 6, qpos = tid & 63;   // wave == one head
    const int qr = qpos >> 3, qc = qpos & 7;
    const int ph = wi * 8 + qr, pw = wj * 8 + qc;

    // q = Qmid[pixel] + pos_q
    float q[8], o[8];
    {
        const float4* qa = (const float4*)(qmid + ((size_t)(ph * W_IMG + pw)) * 64 + head * 8);
        const float4* pq = (const float4*)(pos_q + qpos * 64 + head * 8);
        float4 a0 = qa[0], a1 = qa[1], p0 = pq[0], p1 = pq[1];
        q[0] = a0.x + p0.x; q[1] = a0.y + p0.y; q[2] = a0.z + p0.z; q[3] = a0.w + p0.w;
        q[4] = a1.x + p1.x; q[5] = a1.y + p1.y; q[6] = a1.z + p1.z; q[7] = a1.w + p1.w;
    }
    #pragma unroll
    for (int d = 0; d < 8; ++d) o[d] = 0.f;
    float mx = -3.0e38f, l = 0.f;

    for (int kc = 0; kc < 2; ++kc) {
        __syncthreads();   // protect LDS before (re)staging
        for (int idx = tid; idx < 72 * 16; idx += 512) {
            int kpos = idx >> 4, e4 = idx & 15;
            int kk = kc * 72 + kpos;
            int r = kk / 12, c = kk - r * 12;
            int hh = wi * 8 - 2 + r, ww = wj * 8 - 2 + c;
            float4 kv = {0.f, 0.f, 0.f, 0.f}, vv = {0.f, 0.f, 0.f, 0.f};
            if ((unsigned)hh < 128u && (unsigned)ww < 128u) {
                size_t off = ((size_t)bm * HW + hh * W_IMG + ww) * 16 + e4;
                kv = ((const float4*)kbuf)[off];
                vv = ((const float4*)vbuf)[off];
            }
            float4 pk = ((const float4*)pos_k)[kk * 16 + e4];
            kv.x += pk.x; kv.y += pk.y; kv.z += pk.z; kv.w += pk.w;
            ((float4*)Kt)[idx] = kv;
            ((float4*)Vt)[idx] = vv;
        }
        __syncthreads();

        for (int k = 0; k < 72; ++k) {
            const float4* kr = (const float4*)(Kt + k * 64 + head * 8);  // wave-broadcast
            float4 k0 = kr[0], k1 = kr[1];
            float s = q[0] * k0.x + q[1] * k0.y + q[2] * k0.z + q[3] * k0.w
                    + q[4] * k1.x + q[5] * k1.y + q[6] * k1.z + q[7] * k1.w;
            s *= SCALE;
            float m2 = fmaxf(mx, s);
            float corr = __expf(mx - m2);
            float p = __expf(s - m2);
            l = l * corr + p;
            const float4* vr = (const float4*)(Vt + k * 64 + head * 8);
            float4 v0 = vr[0], v1 = vr[1];
            o[0] = o[0] * corr + p * v0.x; o[1] = o[1] * corr + p * v0.y;
            o[2] = o[2] * corr + p * v0.z; o[3] = o[3] * corr + p * v0.w;
            o[4] = o[4] * corr + p * v1.x; o[5] = o[5] * corr + p * v1.y;
            o[6] = o[6] * corr + p * v1.z; o[7] = o[7] * corr + p * v1.w;
            mx = m2;
        }
    }
    const float inv = 1.f / l;

    __syncthreads();    // everyone done with Kt/Vt
    #pragma unroll
    for (int d = 0; d < 8; ++d) outt[qpos * 65 + head * 8 + d] = o[d] * inv;
    for (int idx = tid; idx < 64 * 64; idx += 512)   // wot[e'*64+e] = w_out[e*64+e']
        wot[idx] = w_out[(idx & 63) * 64 + (idx >> 6)];
    __syncthreads();

    // out-proj + residual + rgb; wave 'grp' handles one pixel per pass, lane = e
    const int lane = tid & 63, grp = tid >> 6;
    const float wr0 = w_rgb[lane], wr1 = w_rgb[64 + lane], wr2 = w_rgb[128 + lane];
    const float br0 = b_rgb[0], br1 = b_rgb[1], br2 = b_rgb[2];
    for (int pass = 0; pass < 8; ++pass) {
        const int q8 = pass * 8 + grp;
        const int rr = q8 >> 3, cc = q8 & 7;
        const int p_ = (wi * 8 + rr) * W_IMG + (wj * 8 + cc);
        float acc = 0.f;
        #pragma unroll 16
        for (int e2 = 0; e2 < 64; ++e2)
            acc = fmaf(outt[q8 * 65 + e2], wot[e2 * 64 + lane], acc);
        const float mixed = acc + feat[((size_t)bm * HW + p_) * 64 + lane];
        float r0 = wr0 * mixed, r1 = wr1 * mixed, r2 = wr2 * mixed;
        #pragma unroll
        for (int oo = 32; oo; oo >>= 1) {
            r0 += __shfl_xor(r0, oo);
            r1 += __shfl_xor(r1, oo);
            r2 += __shfl_xor(r2, oo);
        }
        if (lane == 0) {
            float* dst = outp + (size_t)bm * 3 * HW + p_;
            dst[0]      = r0 + br0;
            dst[HW]     = r1 + br1;
            dst[2 * HW] = r2 + br2;
        }
    }
}

// ---------------------------------------------------------------------------
extern "C" void kernel_launch(void* const* d_in, const int* in_sizes, int n_in,
                              void* d_out, int out_size, void* d_ws, size_t ws_size,
                              hipStream_t stream) {
    const float* x      = (const float*)d_in[0];
    const float* w_high = (const float*)d_in[1];
    const float* b_high = (const float*)d_in[2];
    const float* gamma  = (const float*)d_in[3];
    const float* beta   = (const float*)d_in[4];
    const float* w_qkv  = (const float*)d_in[5];
    const float* pos_q  = (const float*)d_in[6];
    const float* pos_k  = (const float*)d_in[7];
    const float* w_out  = (const float*)d_in[8];
    const float* w_rgb  = (const float*)d_in[9];
    const float* b_rgb  = (const float*)d_in[10];
    float* out = (float*)d_out;

    // workspace carve: 3x (BM,HW,64) + 1x (HW,64) = 64 MiB of fp32
    float* feat = (float*)d_ws;
    float* kbuf = feat + (size_t)BM_TOT * HW * 64;
    float* vbuf = kbuf + (size_t)BM_TOT * HW * 64;
    float* qmid = vbuf + (size_t)BM_TOT * HW * 64;

    k_qkv<<<1024, 256, 0, stream>>>(x, w_high, b_high, gamma, beta, w_qkv,
                                    feat, qmid, kbuf, vbuf);
    k_attn<<<BM_TOT * 256, 512, 0, stream>>>(qmid, kbuf, vbuf, pos_q, pos_k,
                                             w_out, w_rgb, b_rgb, feat, out);
}

// Round 2
// 119.068 us; speedup vs baseline: 2.3590x; 2.3590x over previous
//
#include <hip/hip_runtime.h>

#define HW 16384
#define W_IMG 128
#define BM_TOT 5
#define SCALE 0.35355339059327373f  // 1/sqrt(8)

typedef __attribute__((ext_vector_type(8))) short bf16x8;
typedef __attribute__((ext_vector_type(4))) float f32x4;

__device__ __forceinline__ short f2b(float f) {
    union { float f; unsigned u; } v; v.f = f;
    unsigned r = v.u + 0x7fffu + ((v.u >> 16) & 1u);   // RTNE
    return (short)(r >> 16);
}
__device__ __forceinline__ float b2f(short s) {
    union { unsigned u; float f; } v; v.u = ((unsigned)(unsigned short)s) << 16;
    return v.f;
}
__device__ __forceinline__ unsigned pk2(float a, float b) {
    return ((unsigned)(unsigned short)f2b(a)) | (((unsigned)(unsigned short)f2b(b)) << 16);
}

// ---------------------------------------------------------------------------
// Kernel 1: conv(3->64) + LayerNorm (wave-per-pixel) then MFMA 64x192 proj.
// Block = 64 pixels, 4 waves. Outputs bf16: feat, qmid (frame 2), kbuf, vbuf.
// ---------------------------------------------------------------------------
__global__ __launch_bounds__(256) void k_qkv(
    const float* __restrict__ x, const float* __restrict__ w_high,
    const float* __restrict__ b_high, const float* __restrict__ gamma,
    const float* __restrict__ beta, const float* __restrict__ w_qkv,
    short* __restrict__ feat, short* __restrict__ qmid,
    short* __restrict__ kbuf, short* __restrict__ vbuf)
{
    __shared__ short XS[64 * 72];     // 64 pixels x 64 ch bf16, stride 72
    const int tid = threadIdx.x, wv = tid >> 6, lane = tid & 63;
    const int blk = blockIdx.x;
    const int bm = blk >> 8;                  // 256 blocks per frame
    const int p0 = (blk & 255) * 64;          // in-frame pixel base
    const int pixbase = blk * 64;             // global pixel base

    // ---- phase A: conv + LN for this wave's 16 pixels ----
    const int pw0 = wv * 16;
    float xv = 0.f;
    if ((lane >> 4) < 3)
        xv = x[(size_t)bm * 3 * HW + (lane >> 4) * HW + p0 + pw0 + (lane & 15)];
    const float wh0 = w_high[lane * 3], wh1 = w_high[lane * 3 + 1], wh2 = w_high[lane * 3 + 2];
    const float bh = b_high[lane], gm = gamma[lane], bt = beta[lane];
    #pragma unroll
    for (int t = 0; t < 16; ++t) {
        float x0 = __shfl(xv, t), x1 = __shfl(xv, 16 + t), x2 = __shfl(xv, 32 + t);
        float f = fmaf(wh0, x0, fmaf(wh1, x1, fmaf(wh2, x2, bh)));
        feat[((size_t)pixbase + pw0 + t) * 64 + lane] = f2b(f);
        float s = f, s2 = f * f;
        #pragma unroll
        for (int o = 32; o; o >>= 1) { s += __shfl_xor(s, o); s2 += __shfl_xor(s2, o); }
        float mu = s * 0.015625f;
        float var = s2 * 0.015625f - mu * mu;
        float xs = (f - mu) * rsqrtf(var + 1e-6f) * gm + bt;
        XS[(pw0 + t) * 72 + lane] = f2b(xs);
    }

    // ---- B-fragments from w_qkv (fp32 global, L2-hot) ----
    const int col = lane & 15, grp = lane >> 4;
    bf16x8 Bf[3][2];
    #pragma unroll
    for (int jj = 0; jj < 3; ++jj) {
        int jt = wv + jj * 4;                 // wave handles j-tiles wv, wv+4, wv+8
        #pragma unroll
        for (int kc = 0; kc < 2; ++kc) {
            const float* src = &w_qkv[(jt * 16 + col) * 64 + kc * 32 + grp * 8];
            union { bf16x8 v; unsigned u[4]; } tmp;
            #pragma unroll
            for (int i = 0; i < 4; ++i) tmp.u[i] = pk2(src[2 * i], src[2 * i + 1]);
            Bf[jj][kc] = tmp.v;
        }
    }
    __syncthreads();

    // ---- MFMA: out[pix][j] = xs . w_qkv^T ----
    f32x4 acc[3][4];
    #pragma unroll
    for (int jj = 0; jj < 3; ++jj)
        #pragma unroll
        for (int pt = 0; pt < 4; ++pt) acc[jj][pt] = (f32x4){0.f, 0.f, 0.f, 0.f};
    #pragma unroll
    for (int pt = 0; pt < 4; ++pt) {
        bf16x8 A0 = *(const bf16x8*)&XS[(pt * 16 + col) * 72 + grp * 8];
        bf16x8 A1 = *(const bf16x8*)&XS[(pt * 16 + col) * 72 + 32 + grp * 8];
        #pragma unroll
        for (int jj = 0; jj < 3; ++jj) {
            if (jj == 0 && bm != 2) continue;      // Q needed only for center frame
            acc[jj][pt] = __builtin_amdgcn_mfma_f32_16x16x32_bf16(A0, Bf[jj][0], acc[jj][pt], 0, 0, 0);
            acc[jj][pt] = __builtin_amdgcn_mfma_f32_16x16x32_bf16(A1, Bf[jj][1], acc[jj][pt], 0, 0, 0);
        }
    }

    // ---- store: D row=(l>>4)*4+i = pixel-in-tile, col=l&15 = channel-in-tile ----
    const int ch = wv * 16 + col;
    #pragma unroll
    for (int pt = 0; pt < 4; ++pt) {
        #pragma unroll
        for (int i = 0; i < 4; ++i) {
            int pixl = pt * 16 + grp * 4 + i;
            size_t go = ((size_t)pixbase + pixl) * 64 + ch;
            if (bm == 2) qmid[((size_t)p0 + pixl) * 64 + ch] = f2b(acc[0][pt][i]);
            kbuf[go] = f2b(acc[1][pt][i]);
            vbuf[go] = f2b(acc[2][pt][i]);
        }
    }
}

// ---------------------------------------------------------------------------
// Kernel 2: windowed attention (MFMA) + out-proj + residual + RGB.
// Block = window (bm,wi,wj), 512 threads, wave = head.
// S^T = K.Q^T via mfma (d-axis 8 padded into K=32, zero-padded Q-frag);
// exact single-pass softmax in registers; O^T = V^T.P^T via mfma with P
// round-tripped through a per-head LDS chunk buffer.
// ---------------------------------------------------------------------------
__global__ __launch_bounds__(512) void k_attn(
    const short* __restrict__ qmid, const short* __restrict__ kbuf,
    const short* __restrict__ vbuf, const float* __restrict__ pos_q,
    const float* __restrict__ pos_k, const float* __restrict__ w_out,
    const float* __restrict__ w_rgb, const float* __restrict__ b_rgb,
    const short* __restrict__ feat, float* __restrict__ outp)
{
    __shared__ char smem[52480];
    short* Klds = (short*)smem;                    // [144][72] bf16 (K + pos_k)
    float* Olds = (float*)smem;                    // [64][68] f32 (overlay, after sync)
    short* Vt   = (short*)(smem + 20736);          // [64][168] bf16 (V transposed)
    float* wot  = (float*)(smem + 20736);          // [64][64] f32 (overlay, after sync)
    short* Plds = (short*)(smem + 20736 + 21504);  // [8 heads][16 q][40] bf16 chunk buf

    const int tid = threadIdx.x, blk = blockIdx.x;
    const int bm = blk >> 8, widx = blk & 255;
    const int wi = widx >> 4, wj = widx & 15;
    const int head = tid >> 6, lane = tid & 63;
    const int col = lane & 15, grp = lane >> 4;

    // ---- stage K(+pos_k) row-major and V transposed ----
    for (int idx = tid; idx < 1152; idx += 512) {       // 8 chunks x 144 keys
        int chunk = idx / 144, kk = idx - chunk * 144;
        int r = kk / 12, c = kk - r * 12;
        int hh = wi * 8 - 2 + r, ww = wj * 8 - 2 + c;
        uint4 kraw = {0, 0, 0, 0}, vraw = {0, 0, 0, 0};
        if ((unsigned)hh < 128u && (unsigned)ww < 128u) {
            size_t off = ((size_t)bm * HW + hh * W_IMG + ww) * 64 + chunk * 8;
            kraw = *(const uint4*)&kbuf[off];
            vraw = *(const uint4*)&vbuf[off];
        }
        const float* pk = &pos_k[kk * 64 + chunk * 8];
        union { uint4 q; short s[8]; } ku, vu;
        ku.q = kraw; vu.q = vraw;
        uint4 ko;
        ko.x = pk2(b2f(ku.s[0]) + pk[0], b2f(ku.s[1]) + pk[1]);
        ko.y = pk2(b2f(ku.s[2]) + pk[2], b2f(ku.s[3]) + pk[3]);
        ko.z = pk2(b2f(ku.s[4]) + pk[4], b2f(ku.s[5]) + pk[5]);
        ko.w = pk2(b2f(ku.s[6]) + pk[6], b2f(ku.s[7]) + pk[7]);
        *(uint4*)&Klds[kk * 72 + chunk * 8] = ko;
        #pragma unroll
        for (int cc = 0; cc < 8; ++cc)
            Vt[(chunk * 8 + cc) * 168 + kk] = vu.s[cc];
    }
    {   // zero V^T pad columns [144,160) so PV's padded k' contributes 0 (and no NaN)
        int row = tid >> 3, cc = 144 + (tid & 7) * 2;
        *(unsigned*)&Vt[row * 168 + cc] = 0u;
    }
    __syncthreads();

    // ---- Q-fragments (zero in lane-groups 1-3 => d-axis 8..31 contributes 0) ----
    bf16x8 qf[4];
    #pragma unroll
    for (int qt = 0; qt < 4; ++qt) {
        union { bf16x8 v; unsigned u[4]; } t;
        if (grp == 0) {
            int q = qt * 16 + col;
            int pix = (wi * 8 + (q >> 3)) * W_IMG + wj * 8 + (q & 7);
            const short* qp = &qmid[(size_t)pix * 64 + head * 8];
            const float* pq = &pos_q[q * 64 + head * 8];
            #pragma unroll
            for (int i = 0; i < 4; ++i)
                t.u[i] = pk2(b2f(qp[2 * i]) + pq[2 * i], b2f(qp[2 * i + 1]) + pq[2 * i + 1]);
        } else { t.u[0] = t.u[1] = t.u[2] = t.u[3] = 0; }
        qf[qt] = t.v;
    }

    f32x4 oacc[4];
    float linv[4];
    short* myP = Plds + head * (16 * 40);
    const int prow = col * 40;

    #pragma unroll
    for (int qt = 0; qt < 4; ++qt) {
        // scores S^T tiles: D[m=k'][n=q]
        f32x4 sc[9];
        #pragma unroll
        for (int kt = 0; kt < 9; ++kt) {
            bf16x8 kf = *(const bf16x8*)&Klds[(kt * 16 + col) * 72 + head * 8];
            sc[kt] = __builtin_amdgcn_mfma_f32_16x16x32_bf16(kf, qf[qt], (f32x4){0.f, 0.f, 0.f, 0.f}, 0, 0, 0);
        }
        // exact softmax: 36 in-lane values (all same q=col) + 2 shfl_xor
        float m = -3.0e38f;
        #pragma unroll
        for (int kt = 0; kt < 9; ++kt)
            #pragma unroll
            for (int i = 0; i < 4; ++i) m = fmaxf(m, sc[kt][i]);
        m = fmaxf(m, __shfl_xor(m, 16));
        m = fmaxf(m, __shfl_xor(m, 32));
        float l = 0.f;
        #pragma unroll
        for (int kt = 0; kt < 9; ++kt)
            #pragma unroll
            for (int i = 0; i < 4; ++i) {
                float e = __expf((sc[kt][i] - m) * SCALE);
                sc[kt][i] = e; l += e;
            }
        l += __shfl_xor(l, 16);
        l += __shfl_xor(l, 32);
        linv[qt] = 1.f / l;

        // PV: O^T[d][q] += V^T . P^T over 5 chunks of 32 keys
        f32x4 oa = {0.f, 0.f, 0.f, 0.f};
        #pragma unroll
        for (int kt2 = 0; kt2 < 5; ++kt2) {
            #pragma unroll
            for (int tt = 0; tt < 2; ++tt) {
                int t = kt2 * 2 + tt;
                unsigned d0 = 0, d1 = 0;
                if (t < 9) { d0 = pk2(sc[t][0], sc[t][1]); d1 = pk2(sc[t][2], sc[t][3]); }
                *(unsigned*)&myP[prow + tt * 16 + grp * 4]     = d0;
                *(unsigned*)&myP[prow + tt * 16 + grp * 4 + 2] = d1;
            }
            bf16x8 pf = *(const bf16x8*)&myP[prow + grp * 8];
            bf16x8 vf = *(const bf16x8*)&Vt[(head * 8 + (lane & 7)) * 168 + kt2 * 32 + grp * 8];
            oa = __builtin_amdgcn_mfma_f32_16x16x32_bf16(vf, pf, oa, 0, 0, 0);
        }
        oacc[qt] = oa;
    }
    __syncthreads();   // all K/Vt/P reads done -> safe to overlay O and wot

    if (grp < 2) {     // valid d rows 0..7 live in lane-groups 0,1
        #pragma unroll
        for (int qt = 0; qt < 4; ++qt)
            #pragma unroll
            for (int i = 0; i < 4; ++i)
                Olds[(qt * 16 + col) * 68 + head * 8 + grp * 4 + i] = oacc[qt][i] * linv[qt];
    }
    for (int idx = tid; idx < 4096; idx += 512)
        wot[idx] = w_out[(idx & 63) * 64 + (idx >> 6)];   // wot[e][e'] = w_out[e'][e]
    __syncthreads();

    // ---- epilogue: out-proj + residual + rgb (wave = 8 pixels, lane = e') ----
    const float wr0 = w_rgb[lane], wr1 = w_rgb[64 + lane], wr2 = w_rgb[128 + lane];
    const float br0 = b_rgb[0], br1 = b_rgb[1], br2 = b_rgb[2];
    #pragma unroll 1
    for (int pass = 0; pass < 8; ++pass) {
        int q8 = pass * 8 + head;
        int p_ = (wi * 8 + (q8 >> 3)) * W_IMG + wj * 8 + (q8 & 7);
        float a = 0.f;
        #pragma unroll 16
        for (int e2 = 0; e2 < 64; ++e2)
            a = fmaf(Olds[q8 * 68 + e2], wot[e2 * 64 + lane], a);
        float mixed = a + b2f(feat[((size_t)bm * HW + p_) * 64 + lane]);
        float r0 = wr0 * mixed, r1 = wr1 * mixed, r2 = wr2 * mixed;
        #pragma unroll
        for (int oo = 32; oo; oo >>= 1) {
            r0 += __shfl_xor(r0, oo);
            r1 += __shfl_xor(r1, oo);
            r2 += __shfl_xor(r2, oo);
        }
        if (lane == 0) {
            float* dst = outp + (size_t)bm * 3 * HW + p_;
            dst[0]      = r0 + br0;
            dst[HW]     = r1 + br1;
            dst[2 * HW] = r2 + br2;
        }
    }
}

// ---------------------------------------------------------------------------
extern "C" void kernel_launch(void* const* d_in, const int* in_sizes, int n_in,
                              void* d_out, int out_size, void* d_ws, size_t ws_size,
                              hipStream_t stream) {
    const float* x      = (const float*)d_in[0];
    const float* w_high = (const float*)d_in[1];
    const float* b_high = (const float*)d_in[2];
    const float* gamma  = (const float*)d_in[3];
    const float* beta   = (const float*)d_in[4];
    const float* w_qkv  = (const float*)d_in[5];
    const float* pos_q  = (const float*)d_in[6];
    const float* pos_k  = (const float*)d_in[7];
    const float* w_out  = (const float*)d_in[8];
    const float* w_rgb  = (const float*)d_in[9];
    const float* b_rgb  = (const float*)d_in[10];
    float* out = (float*)d_out;

    // workspace (bf16): feat, kbuf, vbuf (BM,HW,64) + qmid (HW,64)  ~= 34 MB
    short* feat = (short*)d_ws;
    short* kbuf = feat + (size_t)BM_TOT * HW * 64;
    short* vbuf = kbuf + (size_t)BM_TOT * HW * 64;
    short* qmid = vbuf + (size_t)BM_TOT * HW * 64;

    k_qkv<<<BM_TOT * 256, 256, 0, stream>>>(x, w_high, b_high, gamma, beta, w_qkv,
                                            feat, qmid, kbuf, vbuf);
    k_attn<<<BM_TOT * 256, 512, 0, stream>>>(qmid, kbuf, vbuf, pos_q, pos_k,
                                             w_out, w_rgb, b_rgb, feat, out);
}

// Round 3
// 81.047 us; speedup vs baseline: 3.4656x; 1.4691x over previous
//
#include <hip/hip_runtime.h>
#include <hip/hip_bf16.h>

#define HW 16384
#define W_IMG 128
#define BM_TOT 5
#define PRE 0.5101179482f   // (1/sqrt(8)) * log2(e): folded into Q so p = exp2(s-m)

typedef __attribute__((ext_vector_type(8))) short bf16x8;
typedef __attribute__((ext_vector_type(4))) float f32x4;

__device__ __forceinline__ short f2b(float f) {
    __hip_bfloat16 h = __float2bfloat16(f);
    union { __hip_bfloat16 h; short s; } c; c.h = h; return c.s;
}
__device__ __forceinline__ float b2f(short s) {
    union { unsigned u; float f; } v; v.u = ((unsigned)(unsigned short)s) << 16;
    return v.f;
}
__device__ __forceinline__ unsigned pk2(float a, float b) {   // -> v_cvt_pk_bf16_f32
    __hip_bfloat162 h = __float22bfloat162_rn(make_float2(a, b));
    union { __hip_bfloat162 h; unsigned u; } c; c.h = h; return c.u;
}

// ---------------------------------------------------------------------------
// Kernel 1: conv(3->64) + LayerNorm (wave-per-pixel) then MFMA 64x192 proj.
// Block 0 additionally precomputes wcomb = w_rgb @ w_out (bf16, zero-padded
// to 16 rows) and a bf16 copy of w_rgb for the fused k_attn epilogue.
// ---------------------------------------------------------------------------
__global__ __launch_bounds__(256) void k_qkv(
    const float* __restrict__ x, const float* __restrict__ w_high,
    const float* __restrict__ b_high, const float* __restrict__ gamma,
    const float* __restrict__ beta, const float* __restrict__ w_qkv,
    const float* __restrict__ w_out, const float* __restrict__ w_rgb,
    short* __restrict__ feat, short* __restrict__ qmid,
    short* __restrict__ kbuf, short* __restrict__ vbuf,
    short* __restrict__ wcombb, short* __restrict__ wrgbb)
{
    __shared__ short XS[64 * 72];
    const int tid = threadIdx.x, wv = tid >> 6, lane = tid & 63;
    const int blk = blockIdx.x;
    const int bm = blk >> 8;
    const int p0 = (blk & 255) * 64;
    const int pixbase = blk * 64;

    // ---- conv + LN for this wave's 16 pixels ----
    const int pw0 = wv * 16;
    float xv = 0.f;
    if ((lane >> 4) < 3)
        xv = x[(size_t)bm * 3 * HW + (lane >> 4) * HW + p0 + pw0 + (lane & 15)];
    const float wh0 = w_high[lane * 3], wh1 = w_high[lane * 3 + 1], wh2 = w_high[lane * 3 + 2];
    const float bh = b_high[lane], gm = gamma[lane], bt = beta[lane];
    #pragma unroll
    for (int t = 0; t < 16; ++t) {
        float x0 = __shfl(xv, t), x1 = __shfl(xv, 16 + t), x2 = __shfl(xv, 32 + t);
        float f = fmaf(wh0, x0, fmaf(wh1, x1, fmaf(wh2, x2, bh)));
        feat[((size_t)pixbase + pw0 + t) * 64 + lane] = f2b(f);
        float s = f, s2 = f * f;
        #pragma unroll
        for (int o = 32; o; o >>= 1) { s += __shfl_xor(s, o); s2 += __shfl_xor(s2, o); }
        float mu = s * 0.015625f;
        float var = s2 * 0.015625f - mu * mu;
        float xs = (f - mu) * rsqrtf(var + 1e-6f) * gm + bt;
        XS[(pw0 + t) * 72 + lane] = f2b(xs);
    }

    const int col = lane & 15, grp = lane >> 4;
    bf16x8 Bf[3][2];
    #pragma unroll
    for (int jj = 0; jj < 3; ++jj) {
        int jt = wv + jj * 4;
        #pragma unroll
        for (int kc = 0; kc < 2; ++kc) {
            const float* src = &w_qkv[(jt * 16 + col) * 64 + kc * 32 + grp * 8];
            union { bf16x8 v; unsigned u[4]; } tmp;
            #pragma unroll
            for (int i = 0; i < 4; ++i) tmp.u[i] = pk2(src[2 * i], src[2 * i + 1]);
            Bf[jj][kc] = tmp.v;
        }
    }
    __syncthreads();

    f32x4 acc[3][4];
    #pragma unroll
    for (int jj = 0; jj < 3; ++jj)
        #pragma unroll
        for (int pt = 0; pt < 4; ++pt) acc[jj][pt] = (f32x4){0.f, 0.f, 0.f, 0.f};
    #pragma unroll
    for (int pt = 0; pt < 4; ++pt) {
        bf16x8 A0 = *(const bf16x8*)&XS[(pt * 16 + col) * 72 + grp * 8];
        bf16x8 A1 = *(const bf16x8*)&XS[(pt * 16 + col) * 72 + 32 + grp * 8];
        #pragma unroll
        for (int jj = 0; jj < 3; ++jj) {
            if (jj == 0 && bm != 2) continue;
            acc[jj][pt] = __builtin_amdgcn_mfma_f32_16x16x32_bf16(A0, Bf[jj][0], acc[jj][pt], 0, 0, 0);
            acc[jj][pt] = __builtin_amdgcn_mfma_f32_16x16x32_bf16(A1, Bf[jj][1], acc[jj][pt], 0, 0, 0);
        }
    }

    const int ch = wv * 16 + col;
    #pragma unroll
    for (int pt = 0; pt < 4; ++pt) {
        #pragma unroll
        for (int i = 0; i < 4; ++i) {
            int pixl = pt * 16 + grp * 4 + i;
            size_t go = ((size_t)pixbase + pixl) * 64 + ch;
            if (bm == 2) qmid[((size_t)p0 + pixl) * 64 + ch] = f2b(acc[0][pt][i]);
            kbuf[go] = f2b(acc[1][pt][i]);
            vbuf[go] = f2b(acc[2][pt][i]);
        }
    }

    // ---- block 0 tail: wcomb = w_rgb @ w_out, plus bf16 w_rgb (both [16][64] padded) ----
    if (blk == 0) {
        for (int i = tid; i < 1024; i += 256) {
            short wc = 0, wr = 0;
            if (i < 192) {
                int c = i >> 6, e = i & 63;
                float a = 0.f;
                for (int e2 = 0; e2 < 64; ++e2)
                    a = fmaf(w_rgb[c * 64 + e2], w_out[e2 * 64 + e], a);
                wc = f2b(a);
                wr = f2b(w_rgb[i]);
            }
            wcombb[i] = wc;
            wrgbb[i] = wr;
        }
    }
}

// ---------------------------------------------------------------------------
// Kernel 2: windowed attention (MFMA) + fused projection epilogue.
// Block = window, 512 threads, wave = head.
// rgb = (attnout @ wcomb^T) + (feat @ w_rgb^T) + b_rgb  -- all via MFMA.
// ---------------------------------------------------------------------------
__global__ __launch_bounds__(512, 4) void k_attn(
    const short* __restrict__ qmid, const short* __restrict__ kbuf,
    const short* __restrict__ vbuf, const float* __restrict__ pos_q,
    const float* __restrict__ pos_k, const float* __restrict__ b_rgb,
    const short* __restrict__ feat, const short* __restrict__ wcombb,
    const short* __restrict__ wrgbb, float* __restrict__ outp)
{
    __shared__ char smem[58624];
    short* Klds = (short*)smem;                  // [144][72] bf16, K + pos_k
    short* Vt   = (short*)(smem + 20736);        // [64][168] bf16, V transposed
    // PB: per-head 2KB double-buffered P slots at 42240
    short* OL   = (short*)smem;                  // overlay after sync: [64][72] bf16 attn-out

    const int tid = threadIdx.x, blk = blockIdx.x;
    const int bm = blk >> 8, widx = blk & 255;
    const int wi = widx >> 4, wj = widx & 15;
    const int head = tid >> 6, lane = tid & 63;
    const int col = lane & 15, grp = lane >> 4;

    // ---- stage K(+pos_k) row-major and V transposed ----
    for (int idx = tid; idx < 1152; idx += 512) {
        int chunk = idx / 144, kk = idx - chunk * 144;
        int r = kk / 12, c = kk - r * 12;
        int hh = wi * 8 - 2 + r, ww = wj * 8 - 2 + c;
        uint4 kraw = {0, 0, 0, 0}, vraw = {0, 0, 0, 0};
        if ((unsigned)hh < 128u && (unsigned)ww < 128u) {
            size_t off = ((size_t)bm * HW + hh * W_IMG + ww) * 64 + chunk * 8;
            kraw = *(const uint4*)&kbuf[off];
            vraw = *(const uint4*)&vbuf[off];
        }
        const float* pk = &pos_k[kk * 64 + chunk * 8];
        union { uint4 q; short s[8]; } ku, vu;
        ku.q = kraw; vu.q = vraw;
        uint4 ko;
        ko.x = pk2(b2f(ku.s[0]) + pk[0], b2f(ku.s[1]) + pk[1]);
        ko.y = pk2(b2f(ku.s[2]) + pk[2], b2f(ku.s[3]) + pk[3]);
        ko.z = pk2(b2f(ku.s[4]) + pk[4], b2f(ku.s[5]) + pk[5]);
        ko.w = pk2(b2f(ku.s[6]) + pk[6], b2f(ku.s[7]) + pk[7]);
        *(uint4*)&Klds[kk * 72 + chunk * 8] = ko;
        #pragma unroll
        for (int cc = 0; cc < 8; ++cc)
            Vt[(chunk * 8 + cc) * 168 + kk] = vu.s[cc];
    }
    {   // zero V^T pad columns [144,160)
        int row = tid >> 3, cc = 144 + (tid & 7) * 2;
        *(unsigned*)&Vt[row * 168 + cc] = 0u;
    }
    __syncthreads();

    // P slot buffer (per head, double-buffered, conflict-free)
    unsigned* PBh = (unsigned*)(smem + 42240 + head * 2048);
    const int slot_w = (grp * 16 + (col ^ grp)) * 4;                 // u32 units
    const int g0 = 2 * (grp & 1);
    const int slotr1 = (g0 * 16 + (col ^ g0)) * 4 + (grp >> 1) * 2;
    const int slotr2 = ((g0 + 1) * 16 + (col ^ (g0 + 1))) * 4 + (grp >> 1) * 2;

    f32x4 oacc[4];
    float linv[4];

    #pragma unroll
    for (int qt = 0; qt < 4; ++qt) {
        // ---- Q fragment, pre-scaled by SCALE*log2e; zero for grp>0 ----
        bf16x8 qf;
        {
            union { bf16x8 v; unsigned u[4]; } t;
            if (grp == 0) {
                int q = qt * 16 + col;
                int pix = (wi * 8 + (q >> 3)) * W_IMG + wj * 8 + (q & 7);
                union { uint4 raw; short s[8]; } qr;
                qr.raw = *(const uint4*)&qmid[(size_t)pix * 64 + head * 8];
                const float* pq = &pos_q[q * 64 + head * 8];
                #pragma unroll
                for (int i = 0; i < 4; ++i)
                    t.u[i] = pk2((b2f(qr.s[2 * i]) + pq[2 * i]) * PRE,
                                 (b2f(qr.s[2 * i + 1]) + pq[2 * i + 1]) * PRE);
            } else { t.u[0] = t.u[1] = t.u[2] = t.u[3] = 0; }
            qf = t.v;
        }

        // ---- scores S^T: D[k'][q] over 9 key tiles ----
        f32x4 sc[9];
        #pragma unroll
        for (int kt = 0; kt < 9; ++kt) {
            bf16x8 kf = *(const bf16x8*)&Klds[(kt * 16 + col) * 72 + head * 8];
            sc[kt] = __builtin_amdgcn_mfma_f32_16x16x32_bf16(kf, qf, (f32x4){0.f, 0.f, 0.f, 0.f}, 0, 0, 0);
        }

        // ---- exact softmax (36 in-lane + 2 shfl), exp2-based ----
        float m = sc[0][0];
        #pragma unroll
        for (int kt = 0; kt < 9; ++kt)
            #pragma unroll
            for (int i = 0; i < 4; ++i) m = fmaxf(m, sc[kt][i]);
        m = fmaxf(m, __shfl_xor(m, 16));
        m = fmaxf(m, __shfl_xor(m, 32));

        float l = 0.f;
        unsigned pw[20];
        #pragma unroll
        for (int t = 0; t < 9; ++t) {
            float e0 = exp2f(sc[t][0] - m), e1 = exp2f(sc[t][1] - m);
            float e2 = exp2f(sc[t][2] - m), e3 = exp2f(sc[t][3] - m);
            l += (e0 + e1) + (e2 + e3);
            pw[2 * t]     = pk2(e0, e1);
            pw[2 * t + 1] = pk2(e2, e3);
        }
        pw[18] = 0u; pw[19] = 0u;
        l += __shfl_xor(l, 16);
        l += __shfl_xor(l, 32);
        linv[qt] = __builtin_amdgcn_rcpf(l);

        // ---- PV: O^T = V^T . P^T, P via conflict-free slot buffer ----
        *(uint4*)(PBh + slot_w) = make_uint4(pw[0], pw[1], pw[2], pw[3]);
        f32x4 oa = {0.f, 0.f, 0.f, 0.f};
        #pragma unroll
        for (int kt2 = 0; kt2 < 5; ++kt2) {
            unsigned* cur = PBh + (kt2 & 1) * 256;
            uint2 r1 = *(const uint2*)(cur + slotr1);
            uint2 r2 = *(const uint2*)(cur + slotr2);
            if (kt2 < 4)
                *(uint4*)(PBh + ((kt2 + 1) & 1) * 256 + slot_w) =
                    make_uint4(pw[4 * kt2 + 4], pw[4 * kt2 + 5], pw[4 * kt2 + 6], pw[4 * kt2 + 7]);
            union { bf16x8 v; unsigned u[4]; } pf;
            pf.u[0] = r1.x; pf.u[1] = r1.y; pf.u[2] = r2.x; pf.u[3] = r2.y;
            bf16x8 vf = *(const bf16x8*)&Vt[(head * 8 + (lane & 7)) * 168 + kt2 * 32 + grp * 8];
            oa = __builtin_amdgcn_mfma_f32_16x16x32_bf16(vf, pf.v, oa, 0, 0, 0);
        }
        oacc[qt] = oa;
    }

    __syncthreads();   // done with Klds -> overlay OL

    // ---- write normalized attn-out bf16 [q][e] (valid d-rows live in grp 0,1) ----
    if (grp < 2) {
        #pragma unroll
        for (int qt = 0; qt < 4; ++qt) {
            float s = linv[qt];
            uint2 w;
            w.x = pk2(oacc[qt][0] * s, oacc[qt][1] * s);
            w.y = pk2(oacc[qt][2] * s, oacc[qt][3] * s);
            *(uint2*)&OL[(qt * 16 + col) * 72 + head * 8 + grp * 4] = w;
        }
    }
    __syncthreads();

    // ---- fused epilogue: rgb = O@wcomb^T + feat@w_rgb^T + b_rgb (waves 0-3) ----
    if (head < 4) {
        const int qt = head;
        f32x4 acc = {0.f, 0.f, 0.f, 0.f};
        const int q = qt * 16 + col;
        const int pixA = (wi * 8 + (q >> 3)) * W_IMG + wj * 8 + (q & 7);
        #pragma unroll
        for (int kc = 0; kc < 2; ++kc) {
            bf16x8 ao = *(const bf16x8*)&OL[(qt * 16 + col) * 72 + kc * 32 + grp * 8];
            bf16x8 bo = *(const bf16x8*)&wcombb[col * 64 + kc * 32 + grp * 8];
            acc = __builtin_amdgcn_mfma_f32_16x16x32_bf16(ao, bo, acc, 0, 0, 0);
            bf16x8 af = *(const bf16x8*)&feat[((size_t)bm * HW + pixA) * 64 + kc * 32 + grp * 8];
            bf16x8 bf_ = *(const bf16x8*)&wrgbb[col * 64 + kc * 32 + grp * 8];
            acc = __builtin_amdgcn_mfma_f32_16x16x32_bf16(af, bf_, acc, 0, 0, 0);
        }
        if (col < 3) {
            float br = b_rgb[col];
            #pragma unroll
            for (int i = 0; i < 4; ++i) {
                int qs = qt * 16 + grp * 4 + i;
                int pix = (wi * 8 + (qs >> 3)) * W_IMG + wj * 8 + (qs & 7);
                outp[(size_t)bm * 3 * HW + col * HW + pix] = acc[i] + br;
            }
        }
    }
}

// ---------------------------------------------------------------------------
extern "C" void kernel_launch(void* const* d_in, const int* in_sizes, int n_in,
                              void* d_out, int out_size, void* d_ws, size_t ws_size,
                              hipStream_t stream) {
    const float* x      = (const float*)d_in[0];
    const float* w_high = (const float*)d_in[1];
    const float* b_high = (const float*)d_in[2];
    const float* gamma  = (const float*)d_in[3];
    const float* beta   = (const float*)d_in[4];
    const float* w_qkv  = (const float*)d_in[5];
    const float* pos_q  = (const float*)d_in[6];
    const float* pos_k  = (const float*)d_in[7];
    const float* w_out  = (const float*)d_in[8];
    const float* w_rgb  = (const float*)d_in[9];
    const float* b_rgb  = (const float*)d_in[10];
    float* out = (float*)d_out;

    short* feat   = (short*)d_ws;
    short* kbuf   = feat + (size_t)BM_TOT * HW * 64;
    short* vbuf   = kbuf + (size_t)BM_TOT * HW * 64;
    short* qmid   = vbuf + (size_t)BM_TOT * HW * 64;
    short* wcombb = qmid + (size_t)HW * 64;
    short* wrgbb  = wcombb + 1024;

    k_qkv<<<BM_TOT * 256, 256, 0, stream>>>(x, w_high, b_high, gamma, beta, w_qkv,
                                            w_out, w_rgb,
                                            feat, qmid, kbuf, vbuf, wcombb, wrgbb);
    k_attn<<<BM_TOT * 256, 512, 0, stream>>>(qmid, kbuf, vbuf, pos_q, pos_k,
                                             b_rgb, feat, wcombb, wrgbb, out);
}

// Round 4
// 77.188 us; speedup vs baseline: 3.6389x; 1.0500x over previous
//
#include <hip/hip_runtime.h>
#include <hip/hip_bf16.h>

#define HW 16384
#define W_IMG 128
#define BM_TOT 5
#define PRE 0.5101179482f   // (1/sqrt(8)) * log2(e): folded into Q so p = exp2(s-m)

typedef __attribute__((ext_vector_type(8))) short bf16x8;
typedef __attribute__((ext_vector_type(4))) float f32x4;

__device__ __forceinline__ short f2b(float f) {
    __hip_bfloat16 h = __float2bfloat16(f);
    union { __hip_bfloat16 h; short s; } c; c.h = h; return c.s;
}
__device__ __forceinline__ float b2f(short s) {
    union { unsigned u; float f; } v; v.u = ((unsigned)(unsigned short)s) << 16;
    return v.f;
}
__device__ __forceinline__ unsigned pk2(float a, float b) {   // -> v_cvt_pk_bf16_f32
    __hip_bfloat162 h = __float22bfloat162_rn(make_float2(a, b));
    union { __hip_bfloat162 h; unsigned u; } c; c.h = h; return c.u;
}

// ---------------------------------------------------------------------------
// Kernel 1: conv(3->64) + LayerNorm (wave-per-pixel) then MFMA 64x192 proj.
// qmid is stored PRE-SCALED: bf16((q + pos_q) * SCALE*log2e)  (pos_q index
// depends only on pixel%8 since Q windows don't overlap).
// Block 0 precomputes wcomb = w_rgb @ w_out and bf16 w_rgb.
// ---------------------------------------------------------------------------
__global__ __launch_bounds__(256) void k_qkv(
    const float* __restrict__ x, const float* __restrict__ w_high,
    const float* __restrict__ b_high, const float* __restrict__ gamma,
    const float* __restrict__ beta, const float* __restrict__ w_qkv,
    const float* __restrict__ w_out, const float* __restrict__ w_rgb,
    const float* __restrict__ pos_q,
    short* __restrict__ feat, short* __restrict__ qmid,
    short* __restrict__ kbuf, short* __restrict__ vbuf,
    short* __restrict__ wcombb, short* __restrict__ wrgbb)
{
    __shared__ short XS[64 * 72];
    const int tid = threadIdx.x, wv = tid >> 6, lane = tid & 63;
    const int blk = blockIdx.x;
    const int bm = blk >> 8;
    const int p0 = (blk & 255) * 64;
    const int pixbase = blk * 64;

    // ---- conv + LN for this wave's 16 pixels ----
    const int pw0 = wv * 16;
    float xv = 0.f;
    if ((lane >> 4) < 3)
        xv = x[(size_t)bm * 3 * HW + (lane >> 4) * HW + p0 + pw0 + (lane & 15)];
    const float wh0 = w_high[lane * 3], wh1 = w_high[lane * 3 + 1], wh2 = w_high[lane * 3 + 2];
    const float bh = b_high[lane], gm = gamma[lane], bt = beta[lane];
    #pragma unroll
    for (int t = 0; t < 16; ++t) {
        float x0 = __shfl(xv, t), x1 = __shfl(xv, 16 + t), x2 = __shfl(xv, 32 + t);
        float f = fmaf(wh0, x0, fmaf(wh1, x1, fmaf(wh2, x2, bh)));
        feat[((size_t)pixbase + pw0 + t) * 64 + lane] = f2b(f);
        float s = f, s2 = f * f;
        #pragma unroll
        for (int o = 32; o; o >>= 1) { s += __shfl_xor(s, o); s2 += __shfl_xor(s2, o); }
        float mu = s * 0.015625f;
        float var = s2 * 0.015625f - mu * mu;
        float xs = (f - mu) * rsqrtf(var + 1e-6f) * gm + bt;
        XS[(pw0 + t) * 72 + lane] = f2b(xs);
    }

    const int col = lane & 15, grp = lane >> 4;
    bf16x8 Bf[3][2];
    #pragma unroll
    for (int jj = 0; jj < 3; ++jj) {
        int jt = wv + jj * 4;
        #pragma unroll
        for (int kc = 0; kc < 2; ++kc) {
            const float* src = &w_qkv[(jt * 16 + col) * 64 + kc * 32 + grp * 8];
            union { bf16x8 v; unsigned u[4]; } tmp;
            #pragma unroll
            for (int i = 0; i < 4; ++i) tmp.u[i] = pk2(src[2 * i], src[2 * i + 1]);
            Bf[jj][kc] = tmp.v;
        }
    }
    __syncthreads();

    f32x4 acc[3][4];
    #pragma unroll
    for (int jj = 0; jj < 3; ++jj)
        #pragma unroll
        for (int pt = 0; pt < 4; ++pt) acc[jj][pt] = (f32x4){0.f, 0.f, 0.f, 0.f};
    #pragma unroll
    for (int pt = 0; pt < 4; ++pt) {
        bf16x8 A0 = *(const bf16x8*)&XS[(pt * 16 + col) * 72 + grp * 8];
        bf16x8 A1 = *(const bf16x8*)&XS[(pt * 16 + col) * 72 + 32 + grp * 8];
        #pragma unroll
        for (int jj = 0; jj < 3; ++jj) {
            if (jj == 0 && bm != 2) continue;
            acc[jj][pt] = __builtin_amdgcn_mfma_f32_16x16x32_bf16(A0, Bf[jj][0], acc[jj][pt], 0, 0, 0);
            acc[jj][pt] = __builtin_amdgcn_mfma_f32_16x16x32_bf16(A1, Bf[jj][1], acc[jj][pt], 0, 0, 0);
        }
    }

    const int ch = wv * 16 + col;
    #pragma unroll
    for (int pt = 0; pt < 4; ++pt) {
        #pragma unroll
        for (int i = 0; i < 4; ++i) {
            int pixl = pt * 16 + grp * 4 + i;
            size_t go = ((size_t)pixbase + pixl) * 64 + ch;
            if (bm == 2) {
                int p = p0 + pixl;
                int qq = ((p >> 7) & 7) * 8 + (p & 7);
                qmid[(size_t)p * 64 + ch] = f2b((acc[0][pt][i] + pos_q[qq * 64 + ch]) * PRE);
            }
            kbuf[go] = f2b(acc[1][pt][i]);
            vbuf[go] = f2b(acc[2][pt][i]);
        }
    }

    if (blk == 0) {
        for (int i = tid; i < 1024; i += 256) {
            short wc = 0, wr = 0;
            if (i < 192) {
                int c = i >> 6, e = i & 63;
                float a = 0.f;
                for (int e2 = 0; e2 < 64; ++e2)
                    a = fmaf(w_rgb[c * 64 + e2], w_out[e2 * 64 + e], a);
                wc = f2b(a);
                wr = f2b(w_rgb[i]);
            }
            wcombb[i] = wc;
            wrgbb[i] = wr;
        }
    }
}

// ---------------------------------------------------------------------------
// Kernel 2: windowed attention (MFMA) + fused projection epilogue.
// LDS 49.2 KB -> 3 blocks/CU. P slot buffer single-buffered (DS in-order
// within a wave makes the WAR on the per-head private buffer safe).
// ---------------------------------------------------------------------------
__global__ __launch_bounds__(512, 6) void k_attn(
    const short* __restrict__ qmid, const short* __restrict__ kbuf,
    const short* __restrict__ vbuf,
    const float* __restrict__ pos_k, const float* __restrict__ b_rgb,
    const short* __restrict__ feat, const short* __restrict__ wcombb,
    const short* __restrict__ wrgbb, float* __restrict__ outp)
{
    __shared__ char smem[50432];
    short* Klds = (short*)smem;                  // [144][72] bf16, K + pos_k
    short* Vt   = (short*)(smem + 20736);        // [64][168] bf16, V transposed
    short* OL   = (short*)smem;                  // overlay after sync: [64][72] bf16

    const int tid = threadIdx.x, blk = blockIdx.x;
    const int bm = blk >> 8, widx = blk & 255;
    const int wi = widx >> 4, wj = widx & 15;
    const int head = tid >> 6, lane = tid & 63;
    const int col = lane & 15, grp = lane >> 4;

    // ---- stage K(+pos_k) row-major and V transposed ----
    for (int idx = tid; idx < 1152; idx += 512) {
        int chunk = idx / 144, kk = idx - chunk * 144;
        int r = kk / 12, c = kk - r * 12;
        int hh = wi * 8 - 2 + r, ww = wj * 8 - 2 + c;
        uint4 kraw = {0, 0, 0, 0}, vraw = {0, 0, 0, 0};
        if ((unsigned)hh < 128u && (unsigned)ww < 128u) {
            size_t off = ((size_t)bm * HW + hh * W_IMG + ww) * 64 + chunk * 8;
            kraw = *(const uint4*)&kbuf[off];
            vraw = *(const uint4*)&vbuf[off];
        }
        const float* pk = &pos_k[kk * 64 + chunk * 8];
        union { uint4 q; short s[8]; } ku, vu;
        ku.q = kraw; vu.q = vraw;
        uint4 ko;
        ko.x = pk2(b2f(ku.s[0]) + pk[0], b2f(ku.s[1]) + pk[1]);
        ko.y = pk2(b2f(ku.s[2]) + pk[2], b2f(ku.s[3]) + pk[3]);
        ko.z = pk2(b2f(ku.s[4]) + pk[4], b2f(ku.s[5]) + pk[5]);
        ko.w = pk2(b2f(ku.s[6]) + pk[6], b2f(ku.s[7]) + pk[7]);
        *(uint4*)&Klds[kk * 72 + chunk * 8] = ko;
        #pragma unroll
        for (int cc = 0; cc < 8; ++cc)
            Vt[(chunk * 8 + cc) * 168 + kk] = vu.s[cc];
    }
    {   // zero V^T pad columns [144,160)
        int row = tid >> 3, cc = 144 + (tid & 7) * 2;
        *(unsigned*)&Vt[row * 168 + cc] = 0u;
    }

    // ---- Q fragments: direct load, pos_q & scale pre-folded in k_qkv ----
    uint4 qraw[4] = {{0,0,0,0},{0,0,0,0},{0,0,0,0},{0,0,0,0}};
    if (grp == 0) {
        #pragma unroll
        for (int qt = 0; qt < 4; ++qt) {
            int q = qt * 16 + col;
            int pix = (wi * 8 + (q >> 3)) * W_IMG + wj * 8 + (q & 7);
            qraw[qt] = *(const uint4*)&qmid[(size_t)pix * 64 + head * 8];
        }
    }
    __syncthreads();

    // P slot buffer (per head, single-buffered, conflict-free)
    unsigned* PBh = (unsigned*)(smem + 42240 + head * 1024);
    const int slot_w = (grp * 16 + (col ^ grp)) * 4;
    const int g0 = 2 * (grp & 1);
    const int slotr1 = (g0 * 16 + (col ^ g0)) * 4 + (grp >> 1) * 2;
    const int slotr2 = ((g0 + 1) * 16 + (col ^ (g0 + 1))) * 4 + (grp >> 1) * 2;

    f32x4 oacc[4];
    float linv[4];

    #pragma unroll
    for (int qt = 0; qt < 4; ++qt) {
        union { bf16x8 v; uint4 r; } qu; qu.r = qraw[qt];
        const bf16x8 qf = qu.v;

        // ---- scores S^T: D[k'][q] over 9 key tiles ----
        f32x4 sc[9];
        __builtin_amdgcn_s_setprio(1);
        #pragma unroll
        for (int kt = 0; kt < 9; ++kt) {
            bf16x8 kf = *(const bf16x8*)&Klds[(kt * 16 + col) * 72 + head * 8];
            sc[kt] = __builtin_amdgcn_mfma_f32_16x16x32_bf16(kf, qf, (f32x4){0.f, 0.f, 0.f, 0.f}, 0, 0, 0);
        }
        __builtin_amdgcn_s_setprio(0);

        // ---- exact softmax, exp2-based, max3-friendly reduce ----
        float tm[9];
        #pragma unroll
        for (int t = 0; t < 9; ++t)
            tm[t] = fmaxf(fmaxf(sc[t][0], sc[t][1]), fmaxf(sc[t][2], sc[t][3]));
        float m = fmaxf(fmaxf(fmaxf(tm[0], tm[1]), fmaxf(tm[2], tm[3])),
                        fmaxf(fmaxf(tm[4], tm[5]), fmaxf(tm[6], tm[7])));
        m = fmaxf(m, tm[8]);
        m = fmaxf(m, __shfl_xor(m, 16));
        m = fmaxf(m, __shfl_xor(m, 32));

        float l = 0.f;
        unsigned pw[20];
        #pragma unroll
        for (int t = 0; t < 9; ++t) {
            float e0 = exp2f(sc[t][0] - m), e1 = exp2f(sc[t][1] - m);
            float e2 = exp2f(sc[t][2] - m), e3 = exp2f(sc[t][3] - m);
            l += (e0 + e1) + (e2 + e3);
            pw[2 * t]     = pk2(e0, e1);
            pw[2 * t + 1] = pk2(e2, e3);
        }
        pw[18] = 0u; pw[19] = 0u;
        l += __shfl_xor(l, 16);
        l += __shfl_xor(l, 32);
        linv[qt] = __builtin_amdgcn_rcpf(l);

        // ---- PV: O^T = V^T . P^T, P via single-buffer slot exchange ----
        *(uint4*)(PBh + slot_w) = make_uint4(pw[0], pw[1], pw[2], pw[3]);
        f32x4 oa = {0.f, 0.f, 0.f, 0.f};
        __builtin_amdgcn_s_setprio(1);
        #pragma unroll
        for (int kt2 = 0; kt2 < 5; ++kt2) {
            uint2 r1 = *(const uint2*)(PBh + slotr1);
            uint2 r2 = *(const uint2*)(PBh + slotr2);
            if (kt2 < 4)
                *(uint4*)(PBh + slot_w) =
                    make_uint4(pw[4 * kt2 + 4], pw[4 * kt2 + 5], pw[4 * kt2 + 6], pw[4 * kt2 + 7]);
            union { bf16x8 v; unsigned u[4]; } pf;
            pf.u[0] = r1.x; pf.u[1] = r1.y; pf.u[2] = r2.x; pf.u[3] = r2.y;
            bf16x8 vf = *(const bf16x8*)&Vt[(head * 8 + (lane & 7)) * 168 + kt2 * 32 + grp * 8];
            oa = __builtin_amdgcn_mfma_f32_16x16x32_bf16(vf, pf.v, oa, 0, 0, 0);
        }
        __builtin_amdgcn_s_setprio(0);
        oacc[qt] = oa;
    }

    __syncthreads();   // done with Klds -> overlay OL

    if (grp < 2) {
        #pragma unroll
        for (int qt = 0; qt < 4; ++qt) {
            float s = linv[qt];
            uint2 w;
            w.x = pk2(oacc[qt][0] * s, oacc[qt][1] * s);
            w.y = pk2(oacc[qt][2] * s, oacc[qt][3] * s);
            *(uint2*)&OL[(qt * 16 + col) * 72 + head * 8 + grp * 4] = w;
        }
    }
    __syncthreads();

    // ---- fused epilogue: rgb = O@wcomb^T + feat@w_rgb^T + b_rgb (waves 0-3) ----
    if (head < 4) {
        const int qt = head;
        f32x4 acc = {0.f, 0.f, 0.f, 0.f};
        const int q = qt * 16 + col;
        const int pixA = (wi * 8 + (q >> 3)) * W_IMG + wj * 8 + (q & 7);
        #pragma unroll
        for (int kc = 0; kc < 2; ++kc) {
            bf16x8 ao = *(const bf16x8*)&OL[(qt * 16 + col) * 72 + kc * 32 + grp * 8];
            bf16x8 bo = *(const bf16x8*)&wcombb[col * 64 + kc * 32 + grp * 8];
            acc = __builtin_amdgcn_mfma_f32_16x16x32_bf16(ao, bo, acc, 0, 0, 0);
            bf16x8 af = *(const bf16x8*)&feat[((size_t)bm * HW + pixA) * 64 + kc * 32 + grp * 8];
            bf16x8 bf_ = *(const bf16x8*)&wrgbb[col * 64 + kc * 32 + grp * 8];
            acc = __builtin_amdgcn_mfma_f32_16x16x32_bf16(af, bf_, acc, 0, 0, 0);
        }
        if (col < 3) {
            float br = b_rgb[col];
            #pragma unroll
            for (int i = 0; i < 4; ++i) {
                int qs = qt * 16 + grp * 4 + i;
                int pix = (wi * 8 + (qs >> 3)) * W_IMG + wj * 8 + (qs & 7);
                outp[(size_t)bm * 3 * HW + col * HW + pix] = acc[i] + br;
            }
        }
    }
}

// ---------------------------------------------------------------------------
extern "C" void kernel_launch(void* const* d_in, const int* in_sizes, int n_in,
                              void* d_out, int out_size, void* d_ws, size_t ws_size,
                              hipStream_t stream) {
    const float* x      = (const float*)d_in[0];
    const float* w_high = (const float*)d_in[1];
    const float* b_high = (const float*)d_in[2];
    const float* gamma  = (const float*)d_in[3];
    const float* beta   = (const float*)d_in[4];
    const float* w_qkv  = (const float*)d_in[5];
    const float* pos_q  = (const float*)d_in[6];
    const float* pos_k  = (const float*)d_in[7];
    const float* w_out  = (const float*)d_in[8];
    const float* w_rgb  = (const float*)d_in[9];
    const float* b_rgb  = (const float*)d_in[10];
    float* out = (float*)d_out;

    short* feat   = (short*)d_ws;
    short* kbuf   = feat + (size_t)BM_TOT * HW * 64;
    short* vbuf   = kbuf + (size_t)BM_TOT * HW * 64;
    short* qmid   = vbuf + (size_t)BM_TOT * HW * 64;
    short* wcombb = qmid + (size_t)HW * 64;
    short* wrgbb  = wcombb + 1024;

    k_qkv<<<BM_TOT * 256, 256, 0, stream>>>(x, w_high, b_high, gamma, beta, w_qkv,
                                            w_out, w_rgb, pos_q,
                                            feat, qmid, kbuf, vbuf, wcombb, wrgbb);
    k_attn<<<BM_TOT * 256, 512, 0, stream>>>(qmid, kbuf, vbuf, pos_k,
                                             b_rgb, feat, wcombb, wrgbb, out);
}